// Round 2
// baseline (1244.851 us; speedup 1.0000x reference)
//
#include <hip/hip_runtime.h>
#include <cstdint>
#include <cstddef>

// MPNN: 4 edge-conv layers + head MLP.  N=50000, E=800000, F=64.
// Round 2: latency-bound fix. A-fragments loaded DIRECTLY from global (no LDS
// staging), W1/W2 pre-shuffled into fragment order in global ws (prep kernel),
// biases per-lane in registers. Only LDS use: wave-private 32x72 hidden buffer
// for the GEMM1->GEMM2 C->A layout transform. Zero __syncthreads anywhere.
// M=32 edges/wave, 128 edges/block, launch_bounds(256,4) -> 16 waves/CU.

#define NN 50000
#define NE 800000

typedef _Float16 f16;
typedef _Float16 f16x8 __attribute__((ext_vector_type(8)));
typedef float    f32x4 __attribute__((ext_vector_type(4)));

// ---------------------------------------------------------------- small kernels
__global__ void count_kernel(const int* __restrict__ eidx, int* __restrict__ cnt) {
  int i = blockIdx.x * 256 + threadIdx.x;
  if (i < NE) atomicAdd(&cnt[eidx[i]], 1);
}

__global__ void inv_kernel(const int* __restrict__ cnt, float* __restrict__ inv) {
  int v = blockIdx.x * 256 + threadIdx.x;
  if (v < NN) { int c = cnt[v]; inv[v] = 1.0f / (float)(c > 0 ? c : 1); }
}

// mean + relu + re-zero accumulator (so next conv starts from 0)
template<int F32OUT>
__global__ void node_mean_kernel(float* __restrict__ s, const float* __restrict__ inv,
                                 void* __restrict__ xout) {
  int i = blockIdx.x * 256 + threadIdx.x;   // grid covers NN*64 exactly
  float v = fmaxf(s[i] * inv[i >> 6], 0.0f);
  if (F32OUT) ((float*)xout)[i] = v;
  else        ((f16*)xout)[i]   = (f16)v;
  s[i] = 0.0f;
}

// ---------------------------------------------------------------- weight prep
// Shuffle W1 (padded to KSTEPS*32 rows) and W2 into MFMA B-fragment order:
// frag slot (ks,t,lane): dst[slot*8+j] = W[(ks*32+(lane>>4)*8+j)*64 + (t*16+(lane&15))]
__global__ void prep_kernel(const float* __restrict__ W1, int kreal1, int ksteps1,
                            const float* __restrict__ W2,
                            f16* __restrict__ w1f, f16* __restrict__ w2f) {
  int u = blockIdx.x * 256 + threadIdx.x;
  int total1 = ksteps1 * 256;
  const float* W; f16* dst; int kreal, slot;
  if (u < total1)            { W = W1; dst = w1f; kreal = kreal1; slot = u; }
  else if (u < total1 + 512) { W = W2; dst = w2f; kreal = 64;     slot = u - total1; }
  else return;
  int l = slot & 63, t = (slot >> 6) & 3, ks = slot >> 8;
  int n  = t * 16 + (l & 15);
  int kb = ks * 32 + ((l >> 4) * 8);
  f16x8 v;
#pragma unroll
  for (int j = 0; j < 8; ++j) {
    int k = kb + j;
    v[j] = (f16)((k < kreal) ? W[k * 64 + n] : 0.0f);
  }
  *(f16x8*)&dst[slot * 8] = v;
}

// ---------------------------------------------------------------- edge conv
// CONV=1: K=9  (pad 32),  h=[na[r](3), na[c](3), ea(3)]
// CONV=2: K=195(pad 224), h=[x1[r], x1[c], e1, ea(3)]
// CONV=3: K=384,          h=[x2[r],x1[r], x2[c],x1[c], e2,e1]
// CONV=4: K=384,          h=[x3[r],x2[r], x3[c],x2[c], e3,e2]
template<int CONV>
__global__ __launch_bounds__(256, 4) void edge_conv_kernel(
    const int*   __restrict__ eidx,
    const float* __restrict__ na,
    const f16*   __restrict__ xA, const f16* __restrict__ xB,
    const f16*   __restrict__ eA, const f16* __restrict__ eB,
    const float* __restrict__ ea,
    const f16*   __restrict__ w1f, const f16* __restrict__ w2f,
    const float* __restrict__ b1,  const float* __restrict__ b2,
    float* __restrict__ sacc,
    f16* __restrict__ eout_h, float* __restrict__ eout_f)
{
  constexpr int KSTEPS = (CONV == 1) ? 1 : (CONV == 2 ? 7 : 12);

  const int tid  = threadIdx.x;
  const int lane = tid & 63;
  const int wv   = tid >> 6;
  const int quad = lane >> 4;
  const int l15  = lane & 15;

  // wave-private hidden buffer; stride 72 f16 = 144 B (16B-aligned rows,
  // 4-bank offset per row -> at most 2-way read aliasing = free)
  __shared__ __align__(16) f16 hbuf[4][32][72];

  const int ebase = blockIdx.x * 128;
  const int eb0 = ebase + wv * 32 + l15;   // this lane's A-row, subtile 0
  const int eb1 = eb0 + 16;                // subtile 1

  float bb1[4], bb2[4];
#pragma unroll
  for (int t = 0; t < 4; ++t) { bb1[t] = b1[t * 16 + l15]; bb2[t] = b2[t * 16 + l15]; }

  f32x4 acc[2][4];
#pragma unroll
  for (int s = 0; s < 2; ++s)
#pragma unroll
    for (int t = 0; t < 4; ++t) acc[s][t] = (f32x4){0.f, 0.f, 0.f, 0.f};

  const int r0 = eidx[eb0], r1 = eidx[eb1];
  const int c0 = eidx[NE + eb0], c1 = eidx[NE + eb1];

  if constexpr (CONV == 1) {
    f16x8 a0, a1;
#pragma unroll
    for (int j = 0; j < 8; ++j) { a0[j] = (f16)0.0f; a1[j] = (f16)0.0f; }
    if (quad == 0) {
      a0[0] = (f16)na[r0*3];  a0[1] = (f16)na[r0*3+1];  a0[2] = (f16)na[r0*3+2];
      a0[3] = (f16)na[c0*3];  a0[4] = (f16)na[c0*3+1];  a0[5] = (f16)na[c0*3+2];
      a0[6] = (f16)ea[(size_t)eb0*3]; a0[7] = (f16)ea[(size_t)eb0*3+1];
      a1[0] = (f16)na[r1*3];  a1[1] = (f16)na[r1*3+1];  a1[2] = (f16)na[r1*3+2];
      a1[3] = (f16)na[c1*3];  a1[4] = (f16)na[c1*3+1];  a1[5] = (f16)na[c1*3+2];
      a1[6] = (f16)ea[(size_t)eb1*3]; a1[7] = (f16)ea[(size_t)eb1*3+1];
    } else if (quad == 1) {
      a0[0] = (f16)ea[(size_t)eb0*3+2];
      a1[0] = (f16)ea[(size_t)eb1*3+2];
    }
#pragma unroll
    for (int t = 0; t < 4; ++t) {
      f16x8 b = *(const f16x8*)&w1f[(t * 64 + lane) * 8];
      acc[0][t] = __builtin_amdgcn_mfma_f32_16x16x32_f16(a0, b, acc[0][t], 0, 0, 0);
      acc[1][t] = __builtin_amdgcn_mfma_f32_16x16x32_f16(a1, b, acc[1][t], 0, 0, 0);
    }
  } else {
    constexpr int NREG = (CONV == 2) ? 3 : 6;   // regular 64-col chunks
    const f16* p0[NREG]; const f16* p1[NREG];
    if constexpr (CONV == 2) {
      p0[0] = xA + (size_t)r0 * 64;  p1[0] = xA + (size_t)r1 * 64;
      p0[1] = xA + (size_t)c0 * 64;  p1[1] = xA + (size_t)c1 * 64;
      p0[2] = eA + (size_t)eb0 * 64; p1[2] = eA + (size_t)eb1 * 64;
    } else {
      p0[0] = xA + (size_t)r0 * 64;  p1[0] = xA + (size_t)r1 * 64;
      p0[1] = xB + (size_t)r0 * 64;  p1[1] = xB + (size_t)r1 * 64;
      p0[2] = xA + (size_t)c0 * 64;  p1[2] = xA + (size_t)c1 * 64;
      p0[3] = xB + (size_t)c0 * 64;  p1[3] = xB + (size_t)c1 * 64;
      p0[4] = eA + (size_t)eb0 * 64; p1[4] = eA + (size_t)eb1 * 64;
      p0[5] = eB + (size_t)eb0 * 64; p1[5] = eB + (size_t)eb1 * 64;
    }
#pragma unroll
    for (int ks = 0; ks < NREG * 2; ++ks) {
      const int c = ks >> 1, kk = ks & 1;
      f16x8 a0 = *(const f16x8*)(p0[c] + kk * 32 + quad * 8);
      f16x8 a1 = *(const f16x8*)(p1[c] + kk * 32 + quad * 8);
#pragma unroll
      for (int t = 0; t < 4; ++t) {
        f16x8 b = *(const f16x8*)&w1f[((ks * 4 + t) * 64 + lane) * 8];
        acc[0][t] = __builtin_amdgcn_mfma_f32_16x16x32_f16(a0, b, acc[0][t], 0, 0, 0);
        acc[1][t] = __builtin_amdgcn_mfma_f32_16x16x32_f16(a1, b, acc[1][t], 0, 0, 0);
      }
    }
    if constexpr (CONV == 2) {       // tail k-step 6: ea(3) at cols 192..194
      f16x8 a0, a1;
#pragma unroll
      for (int j = 0; j < 8; ++j) { a0[j] = (f16)0.0f; a1[j] = (f16)0.0f; }
      if (quad == 0) {
        a0[0] = (f16)ea[(size_t)eb0*3]; a0[1] = (f16)ea[(size_t)eb0*3+1]; a0[2] = (f16)ea[(size_t)eb0*3+2];
        a1[0] = (f16)ea[(size_t)eb1*3]; a1[1] = (f16)ea[(size_t)eb1*3+1]; a1[2] = (f16)ea[(size_t)eb1*3+2];
      }
#pragma unroll
      for (int t = 0; t < 4; ++t) {
        f16x8 b = *(const f16x8*)&w1f[((6 * 4 + t) * 64 + lane) * 8];
        acc[0][t] = __builtin_amdgcn_mfma_f32_16x16x32_f16(a0, b, acc[0][t], 0, 0, 0);
        acc[1][t] = __builtin_amdgcn_mfma_f32_16x16x32_f16(a1, b, acc[1][t], 0, 0, 0);
      }
    }
  }

  // ---- bias + relu -> wave-private hidden (C-layout write)
#pragma unroll
  for (int s = 0; s < 2; ++s)
#pragma unroll
    for (int t = 0; t < 4; ++t)
#pragma unroll
      for (int r = 0; r < 4; ++r)
        hbuf[wv][s * 16 + quad * 4 + r][t * 16 + l15] =
            (f16)fmaxf(acc[s][t][r] + bb1[t], 0.0f);

  // ---- GEMM2: [32,64] x [64,64] (A-layout read of hidden; B-frags from global)
  f32x4 acc2[2][4];
#pragma unroll
  for (int s = 0; s < 2; ++s)
#pragma unroll
    for (int t = 0; t < 4; ++t) acc2[s][t] = (f32x4){0.f, 0.f, 0.f, 0.f};
#pragma unroll
  for (int kk = 0; kk < 2; ++kk) {
    f16x8 a0 = *(const f16x8*)&hbuf[wv][l15][kk * 32 + quad * 8];
    f16x8 a1 = *(const f16x8*)&hbuf[wv][16 + l15][kk * 32 + quad * 8];
#pragma unroll
    for (int t = 0; t < 4; ++t) {
      f16x8 b = *(const f16x8*)&w2f[((kk * 4 + t) * 64 + lane) * 8];
      acc2[0][t] = __builtin_amdgcn_mfma_f32_16x16x32_f16(a0, b, acc2[0][t], 0, 0, 0);
      acc2[1][t] = __builtin_amdgcn_mfma_f32_16x16x32_f16(a1, b, acc2[1][t], 0, 0, 0);
    }
  }

  // ---- epilogue: scatter raw edge_out to sacc, store relu(edge_out)
#pragma unroll
  for (int s = 0; s < 2; ++s)
#pragma unroll
    for (int r = 0; r < 4; ++r) {
      const int m  = wv * 32 + s * 16 + quad * 4 + r;
      const int rm = eidx[ebase + m];          // L1-hot reload (row index of row m)
      const int eg = ebase + m;
#pragma unroll
      for (int t = 0; t < 4; ++t) {
        const int n = t * 16 + l15;
        float val = acc2[s][t][r] + bb2[t];
        atomicAdd(&sacc[(size_t)rm * 64 + n], val);
        if (CONV < 4) eout_h[(size_t)eg * 64 + n] = (f16)fmaxf(val, 0.0f);
        else          eout_f[(size_t)eg * 64 + n] = fmaxf(val, 0.0f);
      }
    }
}

// ---------------------------------------------------------------- head MLP
__global__ void head_kernel(const float* __restrict__ x4,
                            const float* __restrict__ W1, const float* __restrict__ b1,
                            const float* __restrict__ W2, const float* __restrict__ b2,
                            float* __restrict__ out) {
  __shared__ float xs[4][64];
  __shared__ float hs[4][64];
  int tid = threadIdx.x;
  int i = tid >> 6, f = tid & 63;
  int nb = blockIdx.x * 4;
  xs[i][f] = x4[(size_t)(nb + i) * 64 + f];
  __syncthreads();
  float h = b1[f];
#pragma unroll
  for (int k = 0; k < 64; ++k) h += xs[i][k] * W1[k * 64 + f];
  hs[i][f] = fmaxf(h, 0.0f);
  __syncthreads();
  if (tid < 12) {
    int ii = tid / 3, j = tid % 3;
    float o = b2[j];
#pragma unroll
    for (int k = 0; k < 64; ++k) o += hs[ii][k] * W2[k * 3 + j];
    out[(size_t)(nb + ii) * 3 + j] = o;
  }
}

// ---------------------------------------------------------------- launch
extern "C" void kernel_launch(void* const* d_in, const int* in_sizes, int n_in,
                              void* d_out, int out_size, void* d_ws, size_t ws_size,
                              hipStream_t stream) {
  const float* na   = (const float*)d_in[0];
  const float* ea   = (const float*)d_in[1];
  const int*   eidx = (const int*)d_in[2];
  const float* c1W1 = (const float*)d_in[3];
  const float* c1b1 = (const float*)d_in[4];
  const float* c1W2 = (const float*)d_in[5];
  const float* c1b2 = (const float*)d_in[6];
  const float* c2W1 = (const float*)d_in[7];
  const float* c2b1 = (const float*)d_in[8];
  const float* c2W2 = (const float*)d_in[9];
  const float* c2b2 = (const float*)d_in[10];
  const float* c3W1 = (const float*)d_in[11];
  const float* c3b1 = (const float*)d_in[12];
  const float* c3W2 = (const float*)d_in[13];
  const float* c3b2 = (const float*)d_in[14];
  const float* c4W1 = (const float*)d_in[15];
  const float* c4b1 = (const float*)d_in[16];
  const float* c4W2 = (const float*)d_in[17];
  const float* c4b2 = (const float*)d_in[18];
  const float* mW1  = (const float*)d_in[19];
  const float* mb1  = (const float*)d_in[20];
  const float* mW2  = (const float*)d_in[21];
  const float* mb2  = (const float*)d_in[22];

  char* ws = (char*)d_ws;
  size_t off = 0;
  auto alloc = [&](size_t b) -> void* {
    void* p = ws + off;
    off += (b + 255) & ~(size_t)255;
    return p;
  };
  float* sacc = (float*)alloc((size_t)NN * 64 * 4);
  float* inv  = (float*)alloc((size_t)NN * 4);
  int*   cnt  = (int*)  alloc((size_t)NN * 4);
  f16*   x1   = (f16*)  alloc((size_t)NN * 64 * 2);
  f16*   x2   = (f16*)  alloc((size_t)NN * 64 * 2);
  f16*   x3   = (f16*)  alloc((size_t)NN * 64 * 2);
  float* x4   = (float*)alloc((size_t)NN * 64 * 4);
  f16*   e1   = (f16*)  alloc((size_t)NE * 64 * 2);
  f16*   e2   = (f16*)  alloc((size_t)NE * 64 * 2);
  f16*   e3   = (f16*)  alloc((size_t)NE * 64 * 2);
  // fragment-order weight buffers
  f16* w1f1 = (f16*)alloc((size_t) 1 * 2048 * 2);
  f16* w1f2 = (f16*)alloc((size_t) 7 * 2048 * 2);
  f16* w1f3 = (f16*)alloc((size_t)12 * 2048 * 2);
  f16* w1f4 = (f16*)alloc((size_t)12 * 2048 * 2);
  f16* w2f1 = (f16*)alloc((size_t)4096 * 2);
  f16* w2f2 = (f16*)alloc((size_t)4096 * 2);
  f16* w2f3 = (f16*)alloc((size_t)4096 * 2);
  f16* w2f4 = (f16*)alloc((size_t)4096 * 2);

  float* out_x = (float*)d_out;
  float* out_e = out_x + (size_t)NN * 3;

  hipMemsetAsync(sacc, 0, (size_t)NN * 64 * 4, stream);
  hipMemsetAsync(cnt, 0, (size_t)NN * 4, stream);
  count_kernel<<<NE / 256, 256, 0, stream>>>(eidx, cnt);
  inv_kernel<<<(NN + 255) / 256, 256, 0, stream>>>(cnt, inv);

  prep_kernel<<< 3, 256, 0, stream>>>(c1W1,   9,  1, c1W2, w1f1, w2f1);
  prep_kernel<<< 9, 256, 0, stream>>>(c2W1, 195,  7, c2W2, w1f2, w2f2);
  prep_kernel<<<14, 256, 0, stream>>>(c3W1, 384, 12, c3W2, w1f3, w2f3);
  prep_kernel<<<14, 256, 0, stream>>>(c4W1, 384, 12, c4W2, w1f4, w2f4);

  constexpr int NB = NE / 128;   // 6250

  edge_conv_kernel<1><<<NB, 256, 0, stream>>>(eidx, na, nullptr, nullptr, nullptr, nullptr,
                                              ea, w1f1, w2f1, c1b1, c1b2, sacc, e1, nullptr);
  node_mean_kernel<0><<<NN * 64 / 256, 256, 0, stream>>>(sacc, inv, x1);

  edge_conv_kernel<2><<<NB, 256, 0, stream>>>(eidx, nullptr, x1, nullptr, e1, nullptr,
                                              ea, w1f2, w2f2, c2b1, c2b2, sacc, e2, nullptr);
  node_mean_kernel<0><<<NN * 64 / 256, 256, 0, stream>>>(sacc, inv, x2);

  edge_conv_kernel<3><<<NB, 256, 0, stream>>>(eidx, nullptr, x2, x1, e2, e1,
                                              nullptr, w1f3, w2f3, c3b1, c3b2, sacc, e3, nullptr);
  node_mean_kernel<0><<<NN * 64 / 256, 256, 0, stream>>>(sacc, inv, x3);

  edge_conv_kernel<4><<<NB, 256, 0, stream>>>(eidx, nullptr, x3, x2, e3, e2,
                                              nullptr, w1f4, w2f4, c4b1, c4b2, sacc, nullptr, out_e);
  node_mean_kernel<1><<<NN * 64 / 256, 256, 0, stream>>>(sacc, inv, x4);

  head_kernel<<<NN / 4, 256, 0, stream>>>(x4, mW1, mb1, mW2, mb2, out_x);
}

// Round 3
// 979.717 us; speedup vs baseline: 1.2706x; 1.2706x over previous
//
#include <hip/hip_runtime.h>
#include <cstdint>
#include <cstddef>

// MPNN: 4 edge-conv layers + head MLP.  N=50000, E=800000, F=64.
// Round 3: counting-sort edges by source row each launch. Edge convs process
// edges in sorted order: edge outputs stored RAW f16 in sorted order with
// coalesced stores (LDS transpose); node aggregation = segment sum over
// contiguous ranges (NO atomics, no sacc write-through). W1 fragments in LDS
// (staged once per persistent block); W2 fragments in VGPRs; A-fragments
// gathered directly from global. relu applied on load of e-prev / stored on x.

#define NN 50000
#define NE 800000
#define GRID_EC 512

typedef _Float16 f16;
typedef _Float16 f16x8 __attribute__((ext_vector_type(8)));
typedef _Float16 f16x4 __attribute__((ext_vector_type(4)));
typedef float    f32x4 __attribute__((ext_vector_type(4)));

// ---------------------------------------------------------------- sort build
__global__ void count_kernel(const int* __restrict__ eidx, int* __restrict__ cnt) {
  int i = blockIdx.x * 256 + threadIdx.x;
  if (i < NE) atomicAdd(&cnt[eidx[i]], 1);
}

__global__ void scan_a(const int* __restrict__ cnt, int* __restrict__ bsum) {
  __shared__ int sh[256];
  int i = blockIdx.x * 256 + threadIdx.x;
  sh[threadIdx.x] = (i < NN) ? cnt[i] : 0;
  __syncthreads();
  for (int off = 128; off > 0; off >>= 1) {
    if (threadIdx.x < off) sh[threadIdx.x] += sh[threadIdx.x + off];
    __syncthreads();
  }
  if (threadIdx.x == 0) bsum[blockIdx.x] = sh[0];
}

__global__ void scan_b(const int* __restrict__ bsum, int* __restrict__ boff, int nb) {
  __shared__ int sh[256];
  int t = threadIdx.x;
  int v = (t < nb) ? bsum[t] : 0;
  sh[t] = v; __syncthreads();
  for (int off = 1; off < 256; off <<= 1) {
    int x = (t >= off) ? sh[t - off] : 0;
    __syncthreads();
    sh[t] += x;
    __syncthreads();
  }
  if (t < nb) boff[t] = sh[t] - v;   // exclusive
}

__global__ void scan_c(const int* __restrict__ cnt, const int* __restrict__ boff,
                       int* __restrict__ start, int* __restrict__ cursor) {
  __shared__ int sh[256];
  int t = threadIdx.x;
  int i = blockIdx.x * 256 + t;
  int v = (i < NN) ? cnt[i] : 0;
  sh[t] = v; __syncthreads();
  for (int off = 1; off < 256; off <<= 1) {
    int x = (t >= off) ? sh[t - off] : 0;
    __syncthreads();
    sh[t] += x;
    __syncthreads();
  }
  if (i < NN) {
    int ex = boff[blockIdx.x] + sh[t] - v;
    start[i] = ex; cursor[i] = ex;
  }
  if (i == 0) start[NN] = NE;
}

__global__ void scatter_kernel(const int* __restrict__ eidx, const float* __restrict__ ea,
                               int* __restrict__ cursor,
                               int* __restrict__ srow, int* __restrict__ scol,
                               int* __restrict__ perm, f16* __restrict__ ea4) {
  int e = blockIdx.x * 256 + threadIdx.x;
  if (e >= NE) return;
  int r = eidx[e];
  int j = atomicAdd(&cursor[r], 1);
  srow[j] = r;
  scol[j] = eidx[NE + e];
  perm[j] = e;
  f16x4 v;
  v[0] = (f16)ea[3 * (size_t)e];
  v[1] = (f16)ea[3 * (size_t)e + 1];
  v[2] = (f16)ea[3 * (size_t)e + 2];
  v[3] = (f16)0.0f;
  *(f16x4*)&ea4[4 * (size_t)j] = v;
}

// ---------------------------------------------------------------- weight prep
// frag slot (ks,t,lane): dst[slot*8+j] = W[(ks*32+(lane>>4)*8+j)*64 + (t*16+(lane&15))]
__global__ void prep_kernel(const float* __restrict__ W1, int kreal1, int ksteps1,
                            const float* __restrict__ W2,
                            f16* __restrict__ w1f, f16* __restrict__ w2f) {
  int u = blockIdx.x * 256 + threadIdx.x;
  int total1 = ksteps1 * 256;
  const float* W; f16* dst; int kreal, slot;
  if (u < total1)            { W = W1; dst = w1f; kreal = kreal1; slot = u; }
  else if (u < total1 + 512) { W = W2; dst = w2f; kreal = 64;     slot = u - total1; }
  else return;
  int l = slot & 63, t = (slot >> 6) & 3, ks = slot >> 8;
  int n  = t * 16 + (l & 15);
  int kb = ks * 32 + ((l >> 4) * 8);
  f16x8 v;
#pragma unroll
  for (int j = 0; j < 8; ++j) {
    int k = kb + j;
    v[j] = (f16)((k < kreal) ? W[k * 64 + n] : 0.0f);
  }
  *(f16x8*)&dst[slot * 8] = v;
}

// ---------------------------------------------------------------- node segment sum
// one wave per node: sum raw f16 edge rows over [start[v], start[v+1]) -> relu(mean)
template<int F32OUT>
__global__ void node_sum_kernel(const f16* __restrict__ eout, const int* __restrict__ start,
                                void* __restrict__ xout) {
  int v = blockIdx.x * 4 + (threadIdx.x >> 6);
  int lane = threadIdx.x & 63;
  int g = lane >> 4, c4 = (lane & 15) * 4;
  int s0 = start[v], s1 = start[v + 1];
  f32x4 acc = (f32x4){0.f, 0.f, 0.f, 0.f};
  for (int i = s0 + g; i < s1; i += 4) {
    f16x4 h = *(const f16x4*)&eout[(size_t)i * 64 + c4];
#pragma unroll
    for (int q = 0; q < 4; ++q) acc[q] += (float)h[q];
  }
#pragma unroll
  for (int q = 0; q < 4; ++q) {
    acc[q] += __shfl_xor(acc[q], 16, 64);
    acc[q] += __shfl_xor(acc[q], 32, 64);
  }
  int cv = s1 - s0;
  float inv = 1.0f / (float)(cv > 0 ? cv : 1);
  if (g == 0) {
    if (F32OUT) {
      f32x4 o;
#pragma unroll
      for (int q = 0; q < 4; ++q) o[q] = fmaxf(acc[q] * inv, 0.0f);
      *(f32x4*)&((float*)xout)[(size_t)v * 64 + c4] = o;
    } else {
      f16x4 o;
#pragma unroll
      for (int q = 0; q < 4; ++q) o[q] = (f16)fmaxf(acc[q] * inv, 0.0f);
      *(f16x4*)&((f16*)xout)[(size_t)v * 64 + c4] = o;
    }
  }
}

// ---------------------------------------------------------------- edge conv
// Processes edges in SORTED order j. Writes eout[j] = RAW f16 edge output
// (relu applied by consumers). CONV==4 additionally scatters relu fp32 to
// out_e[perm[j]].
template<int CONV>
__global__ __launch_bounds__(256, 2) void edge_conv_kernel(
    const int* __restrict__ srow, const int* __restrict__ scol,
    const int* __restrict__ perm,
    const float* __restrict__ na,
    const f16* __restrict__ xA, const f16* __restrict__ xB,
    const f16* __restrict__ eA, const f16* __restrict__ eB,
    const f16* __restrict__ ea4,
    const f16* __restrict__ w1f, const f16* __restrict__ w2f,
    const float* __restrict__ b1, const float* __restrict__ b2,
    f16* __restrict__ eout, float* __restrict__ out_e)
{
  constexpr int KSTEPS = (CONV == 1) ? 1 : (CONV == 2 ? 7 : 12);

  __shared__ f16 w1s[KSTEPS * 2048];                 // B-frags, 4KB per ks
  __shared__ __align__(16) f16 hbuf[4][16][72];      // per-wave transform buffer

  const int tid  = threadIdx.x;
  const int lane = tid & 63;
  const int wv   = tid >> 6;
  const int quad = lane >> 4;
  const int l15  = lane & 15;

  for (int u = tid; u < KSTEPS * 256; u += 256)
    *(f16x8*)&w1s[u * 8] = *(const f16x8*)&w1f[u * 8];

  float bb1[4], bb2[4];
#pragma unroll
  for (int t = 0; t < 4; ++t) { bb1[t] = b1[t * 16 + l15]; bb2[t] = b2[t * 16 + l15]; }

  f16x8 w2r[2][4];
#pragma unroll
  for (int kk = 0; kk < 2; ++kk)
#pragma unroll
    for (int t = 0; t < 4; ++t)
      w2r[kk][t] = *(const f16x8*)&w2f[((kk * 4 + t) * 64 + lane) * 8];

  __syncthreads();   // w1s visible; no further barriers

  constexpr int NTILE = NE / 32;          // wave-tiles of 32 edges
  const int gw = blockIdx.x * 4 + wv;

  for (int jt = gw; jt < NTILE; jt += GRID_EC * 4) {
    const int jb = jt * 32;
    const int j0 = jb + l15, j1 = j0 + 16;

    f32x4 acc[2][4];
#pragma unroll
    for (int s = 0; s < 2; ++s)
#pragma unroll
      for (int t = 0; t < 4; ++t) acc[s][t] = (f32x4){0.f, 0.f, 0.f, 0.f};

    if constexpr (CONV == 1) {
      const int r0 = srow[j0], r1 = srow[j1];
      const int c0 = scol[j0], c1 = scol[j1];
      f16x8 a0, a1;
#pragma unroll
      for (int j = 0; j < 8; ++j) { a0[j] = (f16)0.0f; a1[j] = (f16)0.0f; }
      f16x4 q0 = *(const f16x4*)&ea4[4 * (size_t)j0];
      f16x4 q1 = *(const f16x4*)&ea4[4 * (size_t)j1];
      if (quad == 0) {
        a0[0] = (f16)na[r0*3];  a0[1] = (f16)na[r0*3+1];  a0[2] = (f16)na[r0*3+2];
        a0[3] = (f16)na[c0*3];  a0[4] = (f16)na[c0*3+1];  a0[5] = (f16)na[c0*3+2];
        a0[6] = q0[0];          a0[7] = q0[1];
        a1[0] = (f16)na[r1*3];  a1[1] = (f16)na[r1*3+1];  a1[2] = (f16)na[r1*3+2];
        a1[3] = (f16)na[c1*3];  a1[4] = (f16)na[c1*3+1];  a1[5] = (f16)na[c1*3+2];
        a1[6] = q1[0];          a1[7] = q1[1];
      } else if (quad == 1) {
        a0[0] = q0[2];
        a1[0] = q1[2];
      }
#pragma unroll
      for (int t = 0; t < 4; ++t) {
        f16x8 b = *(const f16x8*)&w1s[(t * 64 + lane) * 8];
        acc[0][t] = __builtin_amdgcn_mfma_f32_16x16x32_f16(a0, b, acc[0][t], 0, 0, 0);
        acc[1][t] = __builtin_amdgcn_mfma_f32_16x16x32_f16(a1, b, acc[1][t], 0, 0, 0);
      }
    } else {
      constexpr int NREG = (CONV == 2) ? 3 : 6;
      constexpr int ERCH = (CONV == 2) ? 2 : 4;   // chunks >= ERCH are e-prev (relu)
      const int r0 = srow[j0], r1 = srow[j1];
      const int c0 = scol[j0], c1 = scol[j1];
      const f16* p0[NREG]; const f16* p1[NREG];
      if constexpr (CONV == 2) {
        p0[0] = xA + (size_t)r0 * 64;  p1[0] = xA + (size_t)r1 * 64;
        p0[1] = xA + (size_t)c0 * 64;  p1[1] = xA + (size_t)c1 * 64;
        p0[2] = eA + (size_t)j0 * 64;  p1[2] = eA + (size_t)j1 * 64;
      } else {
        p0[0] = xA + (size_t)r0 * 64;  p1[0] = xA + (size_t)r1 * 64;
        p0[1] = xB + (size_t)r0 * 64;  p1[1] = xB + (size_t)r1 * 64;
        p0[2] = xA + (size_t)c0 * 64;  p1[2] = xA + (size_t)c1 * 64;
        p0[3] = xB + (size_t)c0 * 64;  p1[3] = xB + (size_t)c1 * 64;
        p0[4] = eA + (size_t)j0 * 64;  p1[4] = eA + (size_t)j1 * 64;
        p0[5] = eB + (size_t)j0 * 64;  p1[5] = eB + (size_t)j1 * 64;
      }
#pragma unroll
      for (int ks = 0; ks < NREG * 2; ++ks) {
        const int c = ks >> 1, kk = ks & 1;
        f16x8 a0 = *(const f16x8*)(p0[c] + kk * 32 + quad * 8);
        f16x8 a1 = *(const f16x8*)(p1[c] + kk * 32 + quad * 8);
        if (c >= ERCH) {            // e-prev stored raw -> relu on load
#pragma unroll
          for (int j = 0; j < 8; ++j) {
            a0[j] = (a0[j] > (f16)0.0f) ? a0[j] : (f16)0.0f;
            a1[j] = (a1[j] > (f16)0.0f) ? a1[j] : (f16)0.0f;
          }
        }
#pragma unroll
        for (int t = 0; t < 4; ++t) {
          f16x8 b = *(const f16x8*)&w1s[((ks * 4 + t) * 64 + lane) * 8];
          acc[0][t] = __builtin_amdgcn_mfma_f32_16x16x32_f16(a0, b, acc[0][t], 0, 0, 0);
          acc[1][t] = __builtin_amdgcn_mfma_f32_16x16x32_f16(a1, b, acc[1][t], 0, 0, 0);
        }
      }
      if constexpr (CONV == 2) {    // tail ks 6: ea at cols 192..194
        f16x8 a0, a1;
#pragma unroll
        for (int j = 0; j < 8; ++j) { a0[j] = (f16)0.0f; a1[j] = (f16)0.0f; }
        f16x4 q0 = *(const f16x4*)&ea4[4 * (size_t)j0];
        f16x4 q1 = *(const f16x4*)&ea4[4 * (size_t)j1];
        if (quad == 0) {
          a0[0] = q0[0]; a0[1] = q0[1]; a0[2] = q0[2];
          a1[0] = q1[0]; a1[1] = q1[1]; a1[2] = q1[2];
        }
#pragma unroll
        for (int t = 0; t < 4; ++t) {
          f16x8 b = *(const f16x8*)&w1s[((6 * 4 + t) * 64 + lane) * 8];
          acc[0][t] = __builtin_amdgcn_mfma_f32_16x16x32_f16(a0, b, acc[0][t], 0, 0, 0);
          acc[1][t] = __builtin_amdgcn_mfma_f32_16x16x32_f16(a1, b, acc[1][t], 0, 0, 0);
        }
      }
    }

    // ---- per sub-tile: GEMM2 + stores (wave-private hbuf, in-order DS)
#pragma unroll
    for (int s = 0; s < 2; ++s) {
      // hidden = relu(acc + b1), C-layout -> hbuf
#pragma unroll
      for (int t = 0; t < 4; ++t)
#pragma unroll
        for (int r = 0; r < 4; ++r)
          hbuf[wv][quad * 4 + r][t * 16 + l15] = (f16)fmaxf(acc[s][t][r] + bb1[t], 0.0f);

      f32x4 a2[4];
#pragma unroll
      for (int t = 0; t < 4; ++t) a2[t] = (f32x4){0.f, 0.f, 0.f, 0.f};
#pragma unroll
      for (int kk = 0; kk < 2; ++kk) {
        f16x8 ah = *(const f16x8*)&hbuf[wv][l15][kk * 32 + quad * 8];
#pragma unroll
        for (int t = 0; t < 4; ++t)
          a2[t] = __builtin_amdgcn_mfma_f32_16x16x32_f16(ah, w2r[kk][t], a2[t], 0, 0, 0);
      }

      // raw edge-out f16 -> hbuf (overwrite), then coalesced row stores
#pragma unroll
      for (int t = 0; t < 4; ++t)
#pragma unroll
        for (int r = 0; r < 4; ++r)
          hbuf[wv][quad * 4 + r][t * 16 + l15] = (f16)(a2[t][r] + bb2[t]);

      const int j = jb + s * 16 + l15;
      f16x8 lo = *(const f16x8*)&hbuf[wv][l15][quad * 8];
      f16x8 hi = *(const f16x8*)&hbuf[wv][l15][32 + quad * 8];
      *(f16x8*)&eout[(size_t)j * 64 + quad * 8] = lo;
      *(f16x8*)&eout[(size_t)j * 64 + 32 + quad * 8] = hi;

      if constexpr (CONV == 4) {
        // full-precision relu output, scattered to original edge order
#pragma unroll
        for (int r = 0; r < 4; ++r) {
          const int p = perm[jb + s * 16 + quad * 4 + r];
#pragma unroll
          for (int t = 0; t < 4; ++t)
            out_e[(size_t)p * 64 + t * 16 + l15] = fmaxf(a2[t][r] + bb2[t], 0.0f);
        }
      }
    }
  }
}

// ---------------------------------------------------------------- head MLP
__global__ void head_kernel(const float* __restrict__ x4,
                            const float* __restrict__ W1, const float* __restrict__ b1,
                            const float* __restrict__ W2, const float* __restrict__ b2,
                            float* __restrict__ out) {
  __shared__ float xs[4][64];
  __shared__ float hs[4][64];
  int tid = threadIdx.x;
  int i = tid >> 6, f = tid & 63;
  int nb = blockIdx.x * 4;
  xs[i][f] = x4[(size_t)(nb + i) * 64 + f];
  __syncthreads();
  float h = b1[f];
#pragma unroll
  for (int k = 0; k < 64; ++k) h += xs[i][k] * W1[k * 64 + f];
  hs[i][f] = fmaxf(h, 0.0f);
  __syncthreads();
  if (tid < 12) {
    int ii = tid / 3, j = tid % 3;
    float o = b2[j];
#pragma unroll
    for (int k = 0; k < 64; ++k) o += hs[ii][k] * W2[k * 3 + j];
    out[(size_t)(nb + ii) * 3 + j] = o;
  }
}

// ---------------------------------------------------------------- launch
extern "C" void kernel_launch(void* const* d_in, const int* in_sizes, int n_in,
                              void* d_out, int out_size, void* d_ws, size_t ws_size,
                              hipStream_t stream) {
  const float* na   = (const float*)d_in[0];
  const float* ea   = (const float*)d_in[1];
  const int*   eidx = (const int*)d_in[2];
  const float* c1W1 = (const float*)d_in[3];
  const float* c1b1 = (const float*)d_in[4];
  const float* c1W2 = (const float*)d_in[5];
  const float* c1b2 = (const float*)d_in[6];
  const float* c2W1 = (const float*)d_in[7];
  const float* c2b1 = (const float*)d_in[8];
  const float* c2W2 = (const float*)d_in[9];
  const float* c2b2 = (const float*)d_in[10];
  const float* c3W1 = (const float*)d_in[11];
  const float* c3b1 = (const float*)d_in[12];
  const float* c3W2 = (const float*)d_in[13];
  const float* c3b2 = (const float*)d_in[14];
  const float* c4W1 = (const float*)d_in[15];
  const float* c4b1 = (const float*)d_in[16];
  const float* c4W2 = (const float*)d_in[17];
  const float* c4b2 = (const float*)d_in[18];
  const float* mW1  = (const float*)d_in[19];
  const float* mb1  = (const float*)d_in[20];
  const float* mW2  = (const float*)d_in[21];
  const float* mb2  = (const float*)d_in[22];

  char* ws = (char*)d_ws;
  size_t off = 0;
  auto alloc = [&](size_t b) -> void* {
    void* p = ws + off;
    off += (b + 255) & ~(size_t)255;
    return p;
  };
  int*   cnt    = (int*)alloc((size_t)NN * 4);
  int*   bsum   = (int*)alloc(256 * 4);
  int*   boff   = (int*)alloc(256 * 4);
  int*   start  = (int*)alloc((size_t)(NN + 1) * 4);
  int*   cursor = (int*)alloc((size_t)NN * 4);
  int*   srow   = (int*)alloc((size_t)NE * 4);
  int*   scol   = (int*)alloc((size_t)NE * 4);
  int*   perm   = (int*)alloc((size_t)NE * 4);
  f16*   ea4    = (f16*)alloc((size_t)NE * 4 * 2);
  f16*   x1     = (f16*)alloc((size_t)NN * 64 * 2);
  f16*   x2     = (f16*)alloc((size_t)NN * 64 * 2);
  f16*   x3     = (f16*)alloc((size_t)NN * 64 * 2);
  float* x4     = (float*)alloc((size_t)NN * 64 * 4);
  f16*   se1    = (f16*)alloc((size_t)NE * 64 * 2);   // also reused as e4 raw
  f16*   se2    = (f16*)alloc((size_t)NE * 64 * 2);
  f16*   se3    = (f16*)alloc((size_t)NE * 64 * 2);
  f16*   w1f1 = (f16*)alloc((size_t) 1 * 2048 * 2);
  f16*   w1f2 = (f16*)alloc((size_t) 7 * 2048 * 2);
  f16*   w1f3 = (f16*)alloc((size_t)12 * 2048 * 2);
  f16*   w1f4 = (f16*)alloc((size_t)12 * 2048 * 2);
  f16*   w2f1 = (f16*)alloc((size_t)4096 * 2);
  f16*   w2f2 = (f16*)alloc((size_t)4096 * 2);
  f16*   w2f3 = (f16*)alloc((size_t)4096 * 2);
  f16*   w2f4 = (f16*)alloc((size_t)4096 * 2);

  float* out_x = (float*)d_out;
  float* out_e = out_x + (size_t)NN * 3;

  constexpr int NBS = (NN + 255) / 256;   // 196

  hipMemsetAsync(cnt, 0, (size_t)NN * 4, stream);
  count_kernel<<<NE / 256, 256, 0, stream>>>(eidx, cnt);
  scan_a<<<NBS, 256, 0, stream>>>(cnt, bsum);
  scan_b<<<1, 256, 0, stream>>>(bsum, boff, NBS);
  scan_c<<<NBS, 256, 0, stream>>>(cnt, boff, start, cursor);
  scatter_kernel<<<NE / 256, 256, 0, stream>>>(eidx, ea, cursor, srow, scol, perm, ea4);

  prep_kernel<<< 3, 256, 0, stream>>>(c1W1,   9,  1, c1W2, w1f1, w2f1);
  prep_kernel<<< 9, 256, 0, stream>>>(c2W1, 195,  7, c2W2, w1f2, w2f2);
  prep_kernel<<<14, 256, 0, stream>>>(c3W1, 384, 12, c3W2, w1f3, w2f3);
  prep_kernel<<<14, 256, 0, stream>>>(c4W1, 384, 12, c4W2, w1f4, w2f4);

  edge_conv_kernel<1><<<GRID_EC, 256, 0, stream>>>(srow, scol, nullptr, na,
      nullptr, nullptr, nullptr, nullptr, ea4, w1f1, w2f1, c1b1, c1b2, se1, nullptr);
  node_sum_kernel<0><<<NN / 4, 256, 0, stream>>>(se1, start, x1);

  edge_conv_kernel<2><<<GRID_EC, 256, 0, stream>>>(srow, scol, nullptr, nullptr,
      x1, nullptr, se1, nullptr, ea4, w1f2, w2f2, c2b1, c2b2, se2, nullptr);
  node_sum_kernel<0><<<NN / 4, 256, 0, stream>>>(se2, start, x2);

  edge_conv_kernel<3><<<GRID_EC, 256, 0, stream>>>(srow, scol, nullptr, nullptr,
      x2, x1, se2, se1, nullptr, w1f3, w2f3, c3b1, c3b2, se3, nullptr);
  node_sum_kernel<0><<<NN / 4, 256, 0, stream>>>(se3, start, x3);

  edge_conv_kernel<4><<<GRID_EC, 256, 0, stream>>>(srow, scol, perm, nullptr,
      x3, x2, se3, se2, nullptr, w1f4, w2f4, c4b1, c4b2, se1, out_e);
  node_sum_kernel<1><<<NN / 4, 256, 0, stream>>>(se1, start, x4);

  head_kernel<<<NN / 4, 256, 0, stream>>>(x4, mW1, mb1, mW2, mb2, out_x);
}